// Round 14
// baseline (164.079 us; speedup 1.0000x reference)
//
#include <hip/hip_runtime.h>

#define S_LEN 4096
#define DMODEL 768
#define NHEAD 12
#define HD 64

typedef __bf16 bf16x8 __attribute__((ext_vector_type(8)));
typedef float f32x4 __attribute__((ext_vector_type(4)));
typedef float f32x16 __attribute__((ext_vector_type(16)));
typedef unsigned short u16x8 __attribute__((ext_vector_type(8)));
typedef unsigned short u16x4 __attribute__((ext_vector_type(4)));
typedef _Float16 f16x4 __attribute__((ext_vector_type(4)));

#if __has_builtin(__builtin_amdgcn_exp2f)
#define EXP2F(x) __builtin_amdgcn_exp2f(x)
#else
#define EXP2F(x) exp2f(x)
#endif

#define MFMA32(a, b, c) __builtin_amdgcn_mfma_f32_32x32x16_bf16(a, b, c, 0, 0, 0)

__device__ __forceinline__ unsigned short f2bf(float f) {
  unsigned int u = __float_as_uint(f);
  u += 0x7fffu + ((u >> 16) & 1u);   // round-to-nearest-even
  return (unsigned short)(u >> 16);
}

__device__ __forceinline__ void gload_lds16(const void* g, void* l) {
  __builtin_amdgcn_global_load_lds(
      (__attribute__((address_space(1))) void*)g,
      (__attribute__((address_space(3))) void*)l, 16, 0, 0);
}

// ---------------- fp32 -> bf16 conversion (weights only) ----------------
struct CvtArgs {
  const float* src[4];
  unsigned short* dst[4];
};

__global__ __launch_bounds__(256) void cvt_kernel(CvtArgs a) {
  const int seg = blockIdx.y;
  const int i = (blockIdx.x * 256 + threadIdx.x) * 8;   // DD elems per seg
  const float* s = a.src[seg] + i;
  u16x8 o;
#pragma unroll
  for (int j = 0; j < 8; ++j) o[j] = f2bf(s[j]);
  *reinterpret_cast<u16x8*>(a.dst[seg] + i) = o;
}

// ---------------- fused Q/K/V projection (r11 128^2 tile, verified) ------
struct QkvArgs {
  const float* A[3];
  const unsigned short* W[3];
  const float* bias[3];
  unsigned short* dst[3];
  float scale[3];
};

__global__ __launch_bounds__(256) void qkv_gemm(QkvArgs a) {
  __shared__ unsigned char lds[32768];  // A tile 16KB | W tile 16KB
  const int z = blockIdx.z;
  const float* __restrict__ A = a.A[z];
  const unsigned short* __restrict__ B = a.W[z];
  const float* __restrict__ bias = a.bias[z];
  unsigned short* __restrict__ dst = a.dst[z];
  const float scale = a.scale[z];

  const int tid = threadIdx.x;
  const int lane = tid & 63;
  const int w = tid >> 6;
  const int wr = w >> 1, wc = w & 1;
  const int c = lane & 15, g = lane >> 4;
  const int m0 = blockIdx.x * 128;
  const int n0 = blockIdx.y * 128;

  f32x4 acc[4][4] = {};

  for (int kt = 0; kt < DMODEL / 64; ++kt) {
    // A: fp32 -> bf16 reg staging, swizzled source, linear LDS dest
#pragma unroll
    for (int p = 0; p < 4; ++p) {
      const int te = p * 256 + tid;
      const int row = te >> 3;
      const int sb = ((te & 7) * 16) ^ ((row & 7) << 4);
      const float* src = A + (size_t)(m0 + row) * DMODEL + kt * 64 + (sb >> 1);
      const f32x4 lo = *reinterpret_cast<const f32x4*>(src);
      const f32x4 hi = *reinterpret_cast<const f32x4*>(src + 4);
      bf16x8 v;
#pragma unroll
      for (int j = 0; j < 4; ++j) { v[j] = (__bf16)lo[j]; v[4 + j] = (__bf16)hi[j]; }
      *reinterpret_cast<bf16x8*>(&lds[te * 16]) = v;
    }
    // W: bf16 gload_lds
#pragma unroll
    for (int p = 0; p < 4; ++p) {
      const int te = p * 256 + tid;
      const int row = te >> 3;
      const int sb = ((te & 7) * 16) ^ ((row & 7) << 4);
      gload_lds16(B + (size_t)(n0 + row) * DMODEL + kt * 64 + (sb >> 1),
                  &lds[16384 + te * 16]);
    }
    __syncthreads();

    bf16x8 af[4][2], bfr[4][2];
#pragma unroll
    for (int mb = 0; mb < 4; ++mb)
#pragma unroll
      for (int ks = 0; ks < 2; ++ks) {
        const int row = wr * 64 + mb * 16 + c;
        const int byte = (ks * 64 + g * 16) ^ ((row & 7) << 4);
        af[mb][ks] = *reinterpret_cast<const bf16x8*>(&lds[row * 128 + byte]);
      }
#pragma unroll
    for (int nb = 0; nb < 4; ++nb)
#pragma unroll
      for (int ks = 0; ks < 2; ++ks) {
        const int row = wc * 64 + nb * 16 + c;
        const int byte = (ks * 64 + g * 16) ^ ((row & 7) << 4);
        bfr[nb][ks] = *reinterpret_cast<const bf16x8*>(&lds[16384 + row * 128 + byte]);
      }
    __builtin_amdgcn_s_setprio(1);
#pragma unroll
    for (int ks = 0; ks < 2; ++ks)
#pragma unroll
      for (int mb = 0; mb < 4; ++mb)
#pragma unroll
        for (int nb = 0; nb < 4; ++nb)
          acc[mb][nb] = __builtin_amdgcn_mfma_f32_16x16x32_bf16(
              af[mb][ks], bfr[nb][ks], acc[mb][nb], 0, 0, 0);
    __builtin_amdgcn_s_setprio(0);
    __syncthreads();
  }

#pragma unroll
  for (int mb = 0; mb < 4; ++mb) {
#pragma unroll
    for (int nb = 0; nb < 4; ++nb) {
      const int n = n0 + wc * 64 + nb * 16 + c;
      const float bv = bias[n];
#pragma unroll
      for (int r = 0; r < 4; ++r) {
        const int m = m0 + wr * 64 + mb * 16 + g * 4 + r;
        const float v = (acc[mb][nb][r] + bv) * scale;
        const int hh = n >> 6, hd = n & 63;
        if (z != 2) {
          dst[((size_t)hh * S_LEN + m) * HD + hd] = f2bf(v);
        } else {
          const int mp = (m & ~12) | ((m & 4) << 1) | ((m & 8) >> 1);
          dst[((size_t)hh * HD + hd) * S_LEN + mp] = f2bf(v);
        }
      }
    }
  }
}

// ---------------- output projection (r11 128^2 tile, verified) -----------
__global__ __launch_bounds__(256) void gemm_out(
    const unsigned short* __restrict__ A, const unsigned short* __restrict__ B,
    const float* __restrict__ bias, float* __restrict__ dst) {
  __shared__ unsigned char lds[32768];
  const int tid = threadIdx.x;
  const int lane = tid & 63;
  const int w = tid >> 6;
  const int wr = w >> 1, wc = w & 1;
  const int c = lane & 15, g = lane >> 4;
  const int m0 = blockIdx.x * 128;
  const int n0 = blockIdx.y * 128;

  f32x4 acc[4][4] = {};

  for (int kt = 0; kt < DMODEL / 64; ++kt) {
#pragma unroll
    for (int p = 0; p < 4; ++p) {
      const int te = p * 256 + tid;
      const int row = te >> 3;
      const int sb = ((te & 7) * 16) ^ ((row & 7) << 4);
      gload_lds16(A + (size_t)(m0 + row) * DMODEL + kt * 64 + (sb >> 1), &lds[te * 16]);
      gload_lds16(B + (size_t)(n0 + row) * DMODEL + kt * 64 + (sb >> 1), &lds[16384 + te * 16]);
    }
    __syncthreads();

    bf16x8 af[4][2], bfr[4][2];
#pragma unroll
    for (int mb = 0; mb < 4; ++mb)
#pragma unroll
      for (int ks = 0; ks < 2; ++ks) {
        const int row = wr * 64 + mb * 16 + c;
        const int byte = (ks * 64 + g * 16) ^ ((row & 7) << 4);
        af[mb][ks] = *reinterpret_cast<const bf16x8*>(&lds[row * 128 + byte]);
      }
#pragma unroll
    for (int nb = 0; nb < 4; ++nb)
#pragma unroll
      for (int ks = 0; ks < 2; ++ks) {
        const int row = wc * 64 + nb * 16 + c;
        const int byte = (ks * 64 + g * 16) ^ ((row & 7) << 4);
        bfr[nb][ks] = *reinterpret_cast<const bf16x8*>(&lds[16384 + row * 128 + byte]);
      }
    __builtin_amdgcn_s_setprio(1);
#pragma unroll
    for (int ks = 0; ks < 2; ++ks)
#pragma unroll
      for (int mb = 0; mb < 4; ++mb)
#pragma unroll
        for (int nb = 0; nb < 4; ++nb)
          acc[mb][nb] = __builtin_amdgcn_mfma_f32_16x16x32_bf16(
              af[mb][ks], bfr[nb][ks], acc[mb][nb], 0, 0, 0);
    __builtin_amdgcn_s_setprio(0);
    __syncthreads();
  }

#pragma unroll
  for (int mb = 0; mb < 4; ++mb)
#pragma unroll
    for (int nb = 0; nb < 4; ++nb) {
      const int n = n0 + wc * 64 + nb * 16 + c;
      const float bv = bias[n];
#pragma unroll
      for (int r = 0; r < 4; ++r) {
        const int m = m0 + wr * 64 + mb * 16 + g * 4 + r;
        dst[(size_t)m * DMODEL + n] = acc[mb][nb][r] + bv;
      }
    }
}

// ---------------- flash attention: LDS-free, L1/L2-direct ----------------
// r13 falsified the LDS-BW theory (halving LDS traffic -> 0 change); the
// invariant ~35% MfmaUtil across r9-r13 points at barrier-lockstep stalls.
// K/V tiles (16KB/kt) are L1/L2-resident (Common-mistake #7): read MFMA
// fragments DIRECTLY from global -- same bytes the stager moved, same
// kv-permuted vtp layout. No LDS, no barriers, no vmcnt: waves desync so
// one wave's L2 miss hides under another's compute.
// grid = (S/256, H, 4); block = 256 (4 waves x 64 q, 2 q-tiles/wave from
// r13 -- keeps K/V fragment reuse x2 in regs, now saving L1 BW instead).
__global__ __launch_bounds__(256, 2) void attn_kernel(
    const unsigned short* __restrict__ qh,   // [H][S][64], pre-scaled
    const unsigned short* __restrict__ kh,   // [H][S][64]
    const unsigned short* __restrict__ vtp,  // [H][64][S], kv bits2<->3 swapped
    _Float16* __restrict__ pacc,             // [4][H][S][64] (values /64)
    float* __restrict__ prs) {               // [4][H][S]     (values /64)
  const int tid = threadIdx.x;
  const int lane = tid & 63;
  const int w = tid >> 6;          // 0..3
  const int c5 = lane & 31;
  const int h2 = lane >> 5;
  const int hh = blockIdx.y;
  const int split = blockIdx.z;
  const int qw = blockIdx.x * 256 + w * 64;   // wave owns [qw, qw+64)
  const int kv0 = split * (S_LEN / 4);
  const int nkt = (S_LEN / 4) / 64;   // 16

  // Q B-fragments for both 32-col halves
  bf16x8 qa0[4], qa1[4];
#pragma unroll
  for (int ks = 0; ks < 4; ++ks) {
    qa0[ks] = *reinterpret_cast<const bf16x8*>(
        qh + ((size_t)hh * S_LEN + qw + c5) * HD + ks * 16 + h2 * 8);
    qa1[ks] = *reinterpret_cast<const bf16x8*>(
        qh + ((size_t)hh * S_LEN + qw + 32 + c5) * HD + ks * 16 + h2 * 8);
  }

  f32x16 accO00 = {}, accO01 = {}, accO10 = {}, accO11 = {};  // [half][dt]
  float rsA = 0.f, rsB = 0.f;

  const unsigned short* kb = kh + ((size_t)hh * S_LEN + kv0) * HD;
  const unsigned short* vb = vtp + (size_t)hh * HD * S_LEN + kv0;

  for (int t = 0; t < nkt; ++t) {
    // S^T = mfma(K, Q): K fragments straight from global (row-contiguous)
    f32x16 s0A = {}, s1A = {}, s0B = {}, s1B = {};
#pragma unroll
    for (int ks = 0; ks < 4; ++ks) {
      const int cc = ks * 2 + h2;
      const bf16x8 k0 = *reinterpret_cast<const bf16x8*>(kb + (size_t)c5 * HD + cc * 8);
      const bf16x8 k1 = *reinterpret_cast<const bf16x8*>(kb + (size_t)(32 + c5) * HD + cc * 8);
      __builtin_amdgcn_s_setprio(1);
      s0A = MFMA32(k0, qa0[ks], s0A);
      s0B = MFMA32(k0, qa1[ks], s0B);
      s1A = MFMA32(k1, qa0[ks], s1A);
      s1B = MFMA32(k1, qa1[ks], s1B);
      __builtin_amdgcn_s_setprio(0);
    }

    // fused softmax + PV per 8-kv quadrant; V fragments from global
#pragma unroll
    for (int tq = 0; tq < 2; ++tq)
#pragma unroll
      for (int ss = 0; ss < 2; ++ss) {
        const int cc = tq * 4 + ss * 2 + h2;
        const bf16x8 va0 = *reinterpret_cast<const bf16x8*>(
            vb + (size_t)c5 * S_LEN + cc * 8);
        const bf16x8 va1 = *reinterpret_cast<const bf16x8*>(
            vb + (size_t)(32 + c5) * S_LEN + cc * 8);
        bf16x8 pbA, pbB;
        float ra = 0.f, rb = 0.f;
#pragma unroll
        for (int r = 0; r < 8; ++r) {
          const float eA = EXP2F(tq ? s1A[ss * 8 + r] : s0A[ss * 8 + r]);
          const float eB = EXP2F(tq ? s1B[ss * 8 + r] : s0B[ss * 8 + r]);
          ra += eA; rb += eB;
          pbA[r] = (__bf16)eA;
          pbB[r] = (__bf16)eB;
        }
        rsA += ra; rsB += rb;
        __builtin_amdgcn_s_setprio(1);
        accO00 = MFMA32(va0, pbA, accO00);
        accO01 = MFMA32(va1, pbA, accO01);
        accO10 = MFMA32(va0, pbB, accO10);
        accO11 = MFMA32(va1, pbB, accO11);
        __builtin_amdgcn_s_setprio(0);
      }

    kb += 64 * HD;
    vb += 64;
  }

  // epilogue: per-half row sums + partial writes (scaled 1/64 for f16)
  rsA += __shfl_xor(rsA, 32);
  rsB += __shfl_xor(rsB, 32);
  const size_t hqb0 = ((size_t)split * NHEAD + hh) * S_LEN + qw + c5;
  const size_t hqb1 = hqb0 + 32;
  if (h2 == 0) {
    prs[hqb0] = rsA * 0.015625f;
    prs[hqb1] = rsB * 0.015625f;
  }
#pragma unroll
  for (int dt = 0; dt < 2; ++dt)
#pragma unroll
    for (int rr = 0; rr < 4; ++rr) {
      const int doff = dt * 32 + rr * 8 + h2 * 4;
      f16x4 oA, oB;
#pragma unroll
      for (int j = 0; j < 4; ++j) {
        oA[j] = (_Float16)((dt ? accO01[rr * 4 + j] : accO00[rr * 4 + j]) * 0.015625f);
        oB[j] = (_Float16)((dt ? accO11[rr * 4 + j] : accO10[rr * 4 + j]) * 0.015625f);
      }
      *reinterpret_cast<f16x4*>(pacc + hqb0 * 64 + doff) = oA;
      *reinterpret_cast<f16x4*>(pacc + hqb1 * 64 + doff) = oB;
    }
}

// ---------------- combine 4 kv-split partials -> attb bf16 ---------------
__global__ __launch_bounds__(256) void combine_kernel(
    const _Float16* __restrict__ pacc, const float* __restrict__ prs,
    unsigned short* __restrict__ attb) {
  const int idx = blockIdx.x * 256 + threadIdx.x;  // 786432 total
  const int hq = idx >> 4;            // h*4096 + q
  const int d4 = (idx & 15) * 4;
  const int h = hq >> 12;
  const int q = hq & 4095;
  const int HS = NHEAD * S_LEN;
  const size_t o0 = (size_t)hq * 64 + d4;
  float acc4[4] = {0.f, 0.f, 0.f, 0.f};
  float rs = 0.f;
#pragma unroll
  for (int k = 0; k < 4; ++k) {
    const f16x4 av = *reinterpret_cast<const f16x4*>(pacc + o0 + (size_t)k * HS * 64);
#pragma unroll
    for (int j = 0; j < 4; ++j) acc4[j] += (float)av[j];
    rs += prs[hq + k * HS];
  }
  const float inv = 1.f / rs;
  u16x4 ov;
#pragma unroll
  for (int j = 0; j < 4; ++j) ov[j] = f2bf(acc4[j] * inv);
  *reinterpret_cast<u16x4*>(attb + (size_t)q * DMODEL + h * HD + d4) = ov;
}

// ---------------- launch ----------------
extern "C" void kernel_launch(void* const* d_in, const int* in_sizes, int n_in,
                              void* d_out, int out_size, void* d_ws, size_t ws_size,
                              hipStream_t stream) {
  (void)in_sizes; (void)n_in; (void)out_size;
  const float* q  = (const float*)d_in[0];
  const float* k  = (const float*)d_in[1];
  const float* v  = (const float*)d_in[2];
  const float* Wq = (const float*)d_in[3];
  const float* bq = (const float*)d_in[4];
  const float* Wk = (const float*)d_in[5];
  const float* bk = (const float*)d_in[6];
  const float* Wv = (const float*)d_in[7];
  const float* bv = (const float*)d_in[8];
  const float* Wo = (const float*)d_in[9];
  const float* bo = (const float*)d_in[10];
  float* out = (float*)d_out;

  const size_t SD = (size_t)S_LEN * DMODEL;    // 3145728
  const size_t DD = (size_t)DMODEL * DMODEL;   // 589824
  if (ws_size < (7 * SD + 4 * DD) * 2) return;

  // ws layout (u16 units). Liveness ledger (unchanged from r11):
  //  wqb/wkb/wvb [0..3DD)  -- cvt-written, dead after qkv_gemm.
  //  pacc [0..4SD) f16 [4][H][S][64] -- attn-written, combine-read.
  //  qhb [4SD..5SD) -- attn input; attb aliases it after attn.
  //  khb [5SD..6SD), vtb [6SD..7SD) -- attn inputs.
  //  prs [7SD..7SD+393216) f32 [4][H][S].
  //  wob [7SD+393216..+DD) -- live until gemm_out.
  unsigned short* ws   = (unsigned short*)d_ws;
  unsigned short* wqb  = ws;
  unsigned short* wkb  = ws + DD;
  unsigned short* wvb  = ws + 2 * DD;
  unsigned short* qhb  = ws + 4 * SD;   // [H][S][64]
  unsigned short* khb  = ws + 5 * SD;   // [H][S][64]
  unsigned short* vtb  = ws + 6 * SD;   // [H][64][S] (kv-permuted)
  float*          prs  = (float*)(ws + 7 * SD);          // [4][H][S]
  unsigned short* wob  = ws + 7 * SD + 393216;
  _Float16*       pacc = (_Float16*)ws;                  // [4][H][S][64]
  unsigned short* attb = ws + 4 * SD;                    // alias qhb

  CvtArgs ca;
  ca.src[0] = Wq; ca.dst[0] = wqb;
  ca.src[1] = Wk; ca.dst[1] = wkb;
  ca.src[2] = Wv; ca.dst[2] = wvb;
  ca.src[3] = Wo; ca.dst[3] = wob;
  cvt_kernel<<<dim3(288, 4), 256, 0, stream>>>(ca);   // DD/(8*256) = 288

  QkvArgs qa;
  qa.A[0] = q; qa.W[0] = wqb; qa.bias[0] = bq; qa.dst[0] = qhb;
  qa.scale[0] = 0.18033688011112042f;  // (1/8) * log2(e)
  qa.A[1] = k; qa.W[1] = wkb; qa.bias[1] = bk; qa.dst[1] = khb;
  qa.scale[1] = 1.0f;
  qa.A[2] = v; qa.W[2] = wvb; qa.bias[2] = bv; qa.dst[2] = vtb;
  qa.scale[2] = 1.0f;
  qkv_gemm<<<dim3(32, 6, 3), 256, 0, stream>>>(qa);

  attn_kernel<<<dim3(S_LEN / 256, NHEAD, 4), 256, 0, stream>>>(
      qhb, khb, vtb, pacc, prs);

  combine_kernel<<<dim3((NHEAD * S_LEN * 16) / 256), 256, 0, stream>>>(
      pacc, prs, attb);

  gemm_out<<<dim3(32, 6), 256, 0, stream>>>(attb, wob, bo, out);
}

// Round 15
// 121.197 us; speedup vs baseline: 1.3538x; 1.3538x over previous
//
#include <hip/hip_runtime.h>

#define S_LEN 4096
#define DMODEL 768
#define NHEAD 12
#define HD 64

typedef __bf16 bf16x8 __attribute__((ext_vector_type(8)));
typedef float f32x4 __attribute__((ext_vector_type(4)));
typedef float f32x16 __attribute__((ext_vector_type(16)));
typedef unsigned short u16x8 __attribute__((ext_vector_type(8)));
typedef unsigned short u16x4 __attribute__((ext_vector_type(4)));
typedef _Float16 f16x4 __attribute__((ext_vector_type(4)));

#if __has_builtin(__builtin_amdgcn_exp2f)
#define EXP2F(x) __builtin_amdgcn_exp2f(x)
#else
#define EXP2F(x) exp2f(x)
#endif

#define MFMA32(a, b, c) __builtin_amdgcn_mfma_f32_32x32x16_bf16(a, b, c, 0, 0, 0)

__device__ __forceinline__ unsigned short f2bf(float f) {
  unsigned int u = __float_as_uint(f);
  u += 0x7fffu + ((u >> 16) & 1u);   // round-to-nearest-even
  return (unsigned short)(u >> 16);
}

__device__ __forceinline__ void gload_lds16(const void* g, void* l) {
  __builtin_amdgcn_global_load_lds(
      (__attribute__((address_space(1))) void*)g,
      (__attribute__((address_space(3))) void*)l, 16, 0, 0);
}

// ---------------- fp32 -> bf16 conversion (weights only) ----------------
struct CvtArgs {
  const float* src[4];
  unsigned short* dst[4];
};

__global__ __launch_bounds__(256) void cvt_kernel(CvtArgs a) {
  const int seg = blockIdx.y;
  const int i = (blockIdx.x * 256 + threadIdx.x) * 8;   // DD elems per seg
  const float* s = a.src[seg] + i;
  u16x8 o;
#pragma unroll
  for (int j = 0; j < 8; ++j) o[j] = f2bf(s[j]);
  *reinterpret_cast<u16x8*>(a.dst[seg] + i) = o;
}

// ---------------- fused Q/K/V projection (r11 128^2 tile, verified) ------
struct QkvArgs {
  const float* A[3];
  const unsigned short* W[3];
  const float* bias[3];
  unsigned short* dst[3];
  float scale[3];
};

__global__ __launch_bounds__(256) void qkv_gemm(QkvArgs a) {
  __shared__ unsigned char lds[32768];  // A tile 16KB | W tile 16KB
  const int z = blockIdx.z;
  const float* __restrict__ A = a.A[z];
  const unsigned short* __restrict__ B = a.W[z];
  const float* __restrict__ bias = a.bias[z];
  unsigned short* __restrict__ dst = a.dst[z];
  const float scale = a.scale[z];

  const int tid = threadIdx.x;
  const int lane = tid & 63;
  const int w = tid >> 6;
  const int wr = w >> 1, wc = w & 1;
  const int c = lane & 15, g = lane >> 4;
  const int m0 = blockIdx.x * 128;
  const int n0 = blockIdx.y * 128;

  f32x4 acc[4][4] = {};

  for (int kt = 0; kt < DMODEL / 64; ++kt) {
    // A: fp32 -> bf16 reg staging, swizzled source, linear LDS dest
#pragma unroll
    for (int p = 0; p < 4; ++p) {
      const int te = p * 256 + tid;
      const int row = te >> 3;
      const int sb = ((te & 7) * 16) ^ ((row & 7) << 4);
      const float* src = A + (size_t)(m0 + row) * DMODEL + kt * 64 + (sb >> 1);
      const f32x4 lo = *reinterpret_cast<const f32x4*>(src);
      const f32x4 hi = *reinterpret_cast<const f32x4*>(src + 4);
      bf16x8 v;
#pragma unroll
      for (int j = 0; j < 4; ++j) { v[j] = (__bf16)lo[j]; v[4 + j] = (__bf16)hi[j]; }
      *reinterpret_cast<bf16x8*>(&lds[te * 16]) = v;
    }
    // W: bf16 gload_lds
#pragma unroll
    for (int p = 0; p < 4; ++p) {
      const int te = p * 256 + tid;
      const int row = te >> 3;
      const int sb = ((te & 7) * 16) ^ ((row & 7) << 4);
      gload_lds16(B + (size_t)(n0 + row) * DMODEL + kt * 64 + (sb >> 1),
                  &lds[16384 + te * 16]);
    }
    __syncthreads();

    bf16x8 af[4][2], bfr[4][2];
#pragma unroll
    for (int mb = 0; mb < 4; ++mb)
#pragma unroll
      for (int ks = 0; ks < 2; ++ks) {
        const int row = wr * 64 + mb * 16 + c;
        const int byte = (ks * 64 + g * 16) ^ ((row & 7) << 4);
        af[mb][ks] = *reinterpret_cast<const bf16x8*>(&lds[row * 128 + byte]);
      }
#pragma unroll
    for (int nb = 0; nb < 4; ++nb)
#pragma unroll
      for (int ks = 0; ks < 2; ++ks) {
        const int row = wc * 64 + nb * 16 + c;
        const int byte = (ks * 64 + g * 16) ^ ((row & 7) << 4);
        bfr[nb][ks] = *reinterpret_cast<const bf16x8*>(&lds[16384 + row * 128 + byte]);
      }
    __builtin_amdgcn_s_setprio(1);
#pragma unroll
    for (int ks = 0; ks < 2; ++ks)
#pragma unroll
      for (int mb = 0; mb < 4; ++mb)
#pragma unroll
        for (int nb = 0; nb < 4; ++nb)
          acc[mb][nb] = __builtin_amdgcn_mfma_f32_16x16x32_bf16(
              af[mb][ks], bfr[nb][ks], acc[mb][nb], 0, 0, 0);
    __builtin_amdgcn_s_setprio(0);
    __syncthreads();
  }

#pragma unroll
  for (int mb = 0; mb < 4; ++mb) {
#pragma unroll
    for (int nb = 0; nb < 4; ++nb) {
      const int n = n0 + wc * 64 + nb * 16 + c;
      const float bv = bias[n];
#pragma unroll
      for (int r = 0; r < 4; ++r) {
        const int m = m0 + wr * 64 + mb * 16 + g * 4 + r;
        const float v = (acc[mb][nb][r] + bv) * scale;
        const int hh = n >> 6, hd = n & 63;
        if (z != 2) {
          dst[((size_t)hh * S_LEN + m) * HD + hd] = f2bf(v);
        } else {
          const int mp = (m & ~12) | ((m & 4) << 1) | ((m & 8) >> 1);
          dst[((size_t)hh * HD + hd) * S_LEN + mp] = f2bf(v);
        }
      }
    }
  }
}

// ---------------- output projection (r11 128^2 tile, verified) -----------
__global__ __launch_bounds__(256) void gemm_out(
    const unsigned short* __restrict__ A, const unsigned short* __restrict__ B,
    const float* __restrict__ bias, float* __restrict__ dst) {
  __shared__ unsigned char lds[32768];
  const int tid = threadIdx.x;
  const int lane = tid & 63;
  const int w = tid >> 6;
  const int wr = w >> 1, wc = w & 1;
  const int c = lane & 15, g = lane >> 4;
  const int m0 = blockIdx.x * 128;
  const int n0 = blockIdx.y * 128;

  f32x4 acc[4][4] = {};

  for (int kt = 0; kt < DMODEL / 64; ++kt) {
#pragma unroll
    for (int p = 0; p < 4; ++p) {
      const int te = p * 256 + tid;
      const int row = te >> 3;
      const int sb = ((te & 7) * 16) ^ ((row & 7) << 4);
      gload_lds16(A + (size_t)(m0 + row) * DMODEL + kt * 64 + (sb >> 1), &lds[te * 16]);
      gload_lds16(B + (size_t)(n0 + row) * DMODEL + kt * 64 + (sb >> 1), &lds[16384 + te * 16]);
    }
    __syncthreads();

    bf16x8 af[4][2], bfr[4][2];
#pragma unroll
    for (int mb = 0; mb < 4; ++mb)
#pragma unroll
      for (int ks = 0; ks < 2; ++ks) {
        const int row = wr * 64 + mb * 16 + c;
        const int byte = (ks * 64 + g * 16) ^ ((row & 7) << 4);
        af[mb][ks] = *reinterpret_cast<const bf16x8*>(&lds[row * 128 + byte]);
      }
#pragma unroll
    for (int nb = 0; nb < 4; ++nb)
#pragma unroll
      for (int ks = 0; ks < 2; ++ks) {
        const int row = wc * 64 + nb * 16 + c;
        const int byte = (ks * 64 + g * 16) ^ ((row & 7) << 4);
        bfr[nb][ks] = *reinterpret_cast<const bf16x8*>(&lds[16384 + row * 128 + byte]);
      }
    __builtin_amdgcn_s_setprio(1);
#pragma unroll
    for (int ks = 0; ks < 2; ++ks)
#pragma unroll
      for (int mb = 0; mb < 4; ++mb)
#pragma unroll
        for (int nb = 0; nb < 4; ++nb)
          acc[mb][nb] = __builtin_amdgcn_mfma_f32_16x16x32_bf16(
              af[mb][ks], bfr[nb][ks], acc[mb][nb], 0, 0, 0);
    __builtin_amdgcn_s_setprio(0);
    __syncthreads();
  }

#pragma unroll
  for (int mb = 0; mb < 4; ++mb)
#pragma unroll
    for (int nb = 0; nb < 4; ++nb) {
      const int n = n0 + wc * 64 + nb * 16 + c;
      const float bv = bias[n];
#pragma unroll
      for (int r = 0; r < 4; ++r) {
        const int m = m0 + wr * 64 + mb * 16 + g * 4 + r;
        dst[(size_t)m * DMODEL + n] = acc[mb][nb][r] + bv;
      }
    }
}

// ---------------- flash attention: 2 q-tiles per wave (r13, verified) ----
// Best-known attn (62us, MfmaUtil ~35, conflicts 0). r14 proved LDS
// staging is load-bearing (global-direct fragments -> 109us): block-shared
// gload_lds amortizes load issue 4x across waves. r13 proved LDS BW is
// NOT binding (2x fragment reuse -> 0 delta). Plateau of this family.
// grid = (S/256, H, 4); block = 256 (4 waves x 64 q). KV tile 64.
// Triple buffer, one barrier/kt, prefetch depth 2, counted vmcnt(4).
__global__ __launch_bounds__(256, 2) void attn_kernel(
    const unsigned short* __restrict__ qh,   // [H][S][64], pre-scaled
    const unsigned short* __restrict__ kh,   // [H][S][64]
    const unsigned short* __restrict__ vtp,  // [H][64][S], kv bits2<->3 swapped
    _Float16* __restrict__ pacc,             // [4][H][S][64] (values /64)
    float* __restrict__ prs) {               // [4][H][S]     (values /64)
  __shared__ unsigned char lds[49152];  // 3 x (K 8KB | Vt 8KB)
  const int tid = threadIdx.x;
  const int lane = tid & 63;
  const int w = tid >> 6;          // 0..3
  const int c5 = lane & 31;
  const int h2 = lane >> 5;
  const int hh = blockIdx.y;
  const int split = blockIdx.z;
  const int qw = blockIdx.x * 256 + w * 64;   // wave owns [qw, qw+64)
  const int kv0 = split * (S_LEN / 4);
  const int nkt = (S_LEN / 4) / 64;   // 16

  // Q B-fragments for both 32-col halves: col = q = qw + h*32 + c5
  bf16x8 qa0[4], qa1[4];
#pragma unroll
  for (int ks = 0; ks < 4; ++ks) {
    qa0[ks] = *reinterpret_cast<const bf16x8*>(
        qh + ((size_t)hh * S_LEN + qw + c5) * HD + ks * 16 + h2 * 8);
    qa1[ks] = *reinterpret_cast<const bf16x8*>(
        qh + ((size_t)hh * S_LEN + qw + 32 + c5) * HD + ks * 16 + h2 * 8);
  }

  // transposed-chunk staging: 256 threads, 4 x 16B each
  const unsigned short* ksrc =
      kh + ((size_t)hh * S_LEN + kv0 + (tid & 63)) * HD + (tid >> 6) * 8;
  const unsigned short* vsrc =
      vtp + ((size_t)hh * HD + (tid & 63)) * S_LEN + kv0 + (tid >> 6) * 8;
  const int dL = tid * 16;

  auto stage = [&](int bo) {
    gload_lds16(ksrc, &lds[bo + dL]);
    gload_lds16(ksrc + 32, &lds[bo + 4096 + dL]);   // kchunks 4..7
    gload_lds16(vsrc, &lds[bo + 8192 + dL]);
    gload_lds16(vsrc + 32, &lds[bo + 12288 + dL]);
    ksrc += 64 * HD;
    vsrc += 64;
  };

  stage(0);
  stage(16384);

  f32x16 accO00 = {}, accO01 = {}, accO10 = {}, accO11 = {};  // [half][dt]
  float rsA = 0.f, rsB = 0.f;

  auto compute = [&](const unsigned char* Kb, const unsigned char* Vb) {
    // S^T = mfma(K, Q) for both halves; K regs shared across halves
    f32x16 s0A = {}, s1A = {}, s0B = {}, s1B = {};
    __builtin_amdgcn_s_setprio(1);
#pragma unroll
    for (int ks = 0; ks < 4; ++ks) {
      const unsigned char* kbase = Kb + (ks * 2 + h2) * 1024 + c5 * 16;
      const bf16x8 k0 = *reinterpret_cast<const bf16x8*>(kbase);
      const bf16x8 k1 = *reinterpret_cast<const bf16x8*>(kbase + 512);
      s0A = MFMA32(k0, qa0[ks], s0A);
      s0B = MFMA32(k0, qa1[ks], s0B);
      s1A = MFMA32(k1, qa0[ks], s1A);
      s1B = MFMA32(k1, qa1[ks], s1B);
    }
    __builtin_amdgcn_s_setprio(0);

    // fused softmax + PV per 8-kv quadrant; V regs shared across halves
#pragma unroll
    for (int t = 0; t < 2; ++t)
#pragma unroll
      for (int ss = 0; ss < 2; ++ss) {
        const unsigned char* vbase = Vb + (t * 4 + ss * 2 + h2) * 1024 + c5 * 16;
        const bf16x8 va0 = *reinterpret_cast<const bf16x8*>(vbase);
        const bf16x8 va1 = *reinterpret_cast<const bf16x8*>(vbase + 512);
        bf16x8 pbA, pbB;
        float ra = 0.f, rb = 0.f;
#pragma unroll
        for (int r = 0; r < 8; ++r) {
          const float eA = EXP2F(t ? s1A[ss * 8 + r] : s0A[ss * 8 + r]);
          const float eB = EXP2F(t ? s1B[ss * 8 + r] : s0B[ss * 8 + r]);
          ra += eA; rb += eB;
          pbA[r] = (__bf16)eA;
          pbB[r] = (__bf16)eB;
        }
        rsA += ra; rsB += rb;
        __builtin_amdgcn_s_setprio(1);
        accO00 = MFMA32(va0, pbA, accO00);
        accO01 = MFMA32(va1, pbA, accO01);
        accO10 = MFMA32(va0, pbB, accO10);
        accO11 = MFMA32(va1, pbB, accO11);
        __builtin_amdgcn_s_setprio(0);
      }
  };

  int boC = 0;
  int boS = 32768;
  for (int t = 0; t < nkt; ++t) {
    if (t + 2 < nkt) {
      asm volatile("s_waitcnt vmcnt(4)" ::: "memory");
      __builtin_amdgcn_sched_barrier(0);
      __builtin_amdgcn_s_barrier();
      __builtin_amdgcn_sched_barrier(0);
      stage(boS);
    } else if (t + 1 < nkt) {
      asm volatile("s_waitcnt vmcnt(4)" ::: "memory");
      __builtin_amdgcn_sched_barrier(0);
      __builtin_amdgcn_s_barrier();
      __builtin_amdgcn_sched_barrier(0);
    } else {
      asm volatile("s_waitcnt vmcnt(0)" ::: "memory");
      __builtin_amdgcn_sched_barrier(0);
      __builtin_amdgcn_s_barrier();
      __builtin_amdgcn_sched_barrier(0);
    }
    compute(&lds[boC], &lds[boC + 8192]);
    boC += 16384; if (boC == 49152) boC = 0;
    boS += 16384; if (boS == 49152) boS = 0;
  }

  // epilogue: per-half row sums + partial writes (scaled 1/64 for f16)
  rsA += __shfl_xor(rsA, 32);
  rsB += __shfl_xor(rsB, 32);
  const size_t hqb0 = ((size_t)split * NHEAD + hh) * S_LEN + qw + c5;
  const size_t hqb1 = hqb0 + 32;
  if (h2 == 0) {
    prs[hqb0] = rsA * 0.015625f;
    prs[hqb1] = rsB * 0.015625f;
  }
#pragma unroll
  for (int dt = 0; dt < 2; ++dt)
#pragma unroll
    for (int rr = 0; rr < 4; ++rr) {
      const int doff = dt * 32 + rr * 8 + h2 * 4;
      f16x4 oA, oB;
#pragma unroll
      for (int j = 0; j < 4; ++j) {
        oA[j] = (_Float16)((dt ? accO01[rr * 4 + j] : accO00[rr * 4 + j]) * 0.015625f);
        oB[j] = (_Float16)((dt ? accO11[rr * 4 + j] : accO10[rr * 4 + j]) * 0.015625f);
      }
      *reinterpret_cast<f16x4*>(pacc + hqb0 * 64 + doff) = oA;
      *reinterpret_cast<f16x4*>(pacc + hqb1 * 64 + doff) = oB;
    }
}

// ---------------- combine 4 kv-split partials -> attb bf16 ---------------
__global__ __launch_bounds__(256) void combine_kernel(
    const _Float16* __restrict__ pacc, const float* __restrict__ prs,
    unsigned short* __restrict__ attb) {
  const int idx = blockIdx.x * 256 + threadIdx.x;  // 786432 total
  const int hq = idx >> 4;            // h*4096 + q
  const int d4 = (idx & 15) * 4;
  const int h = hq >> 12;
  const int q = hq & 4095;
  const int HS = NHEAD * S_LEN;
  const size_t o0 = (size_t)hq * 64 + d4;
  float acc4[4] = {0.f, 0.f, 0.f, 0.f};
  float rs = 0.f;
#pragma unroll
  for (int k = 0; k < 4; ++k) {
    const f16x4 av = *reinterpret_cast<const f16x4*>(pacc + o0 + (size_t)k * HS * 64);
#pragma unroll
    for (int j = 0; j < 4; ++j) acc4[j] += (float)av[j];
    rs += prs[hq + k * HS];
  }
  const float inv = 1.f / rs;
  u16x4 ov;
#pragma unroll
  for (int j = 0; j < 4; ++j) ov[j] = f2bf(acc4[j] * inv);
  *reinterpret_cast<u16x4*>(attb + (size_t)q * DMODEL + h * HD + d4) = ov;
}

// ---------------- launch ----------------
extern "C" void kernel_launch(void* const* d_in, const int* in_sizes, int n_in,
                              void* d_out, int out_size, void* d_ws, size_t ws_size,
                              hipStream_t stream) {
  (void)in_sizes; (void)n_in; (void)out_size;
  const float* q  = (const float*)d_in[0];
  const float* k  = (const float*)d_in[1];
  const float* v  = (const float*)d_in[2];
  const float* Wq = (const float*)d_in[3];
  const float* bq = (const float*)d_in[4];
  const float* Wk = (const float*)d_in[5];
  const float* bk = (const float*)d_in[6];
  const float* Wv = (const float*)d_in[7];
  const float* bv = (const float*)d_in[8];
  const float* Wo = (const float*)d_in[9];
  const float* bo = (const float*)d_in[10];
  float* out = (float*)d_out;

  const size_t SD = (size_t)S_LEN * DMODEL;    // 3145728
  const size_t DD = (size_t)DMODEL * DMODEL;   // 589824
  if (ws_size < (7 * SD + 4 * DD) * 2) return;

  // ws layout (u16 units). Liveness ledger:
  //  wqb/wkb/wvb [0..3DD)  -- cvt-written, dead after qkv_gemm.
  //  pacc [0..4SD) f16 [4][H][S][64] -- attn-written, combine-read.
  //  qhb [4SD..5SD) -- attn input; attb aliases it after attn.
  //  khb [5SD..6SD), vtb [6SD..7SD) -- attn inputs.
  //  prs [7SD..7SD+393216) f32 [4][H][S].
  //  wob [7SD+393216..+DD) -- live until gemm_out.
  unsigned short* ws   = (unsigned short*)d_ws;
  unsigned short* wqb  = ws;
  unsigned short* wkb  = ws + DD;
  unsigned short* wvb  = ws + 2 * DD;
  unsigned short* qhb  = ws + 4 * SD;   // [H][S][64]
  unsigned short* khb  = ws + 5 * SD;   // [H][S][64]
  unsigned short* vtb  = ws + 6 * SD;   // [H][64][S] (kv-permuted)
  float*          prs  = (float*)(ws + 7 * SD);          // [4][H][S]
  unsigned short* wob  = ws + 7 * SD + 393216;
  _Float16*       pacc = (_Float16*)ws;                  // [4][H][S][64]
  unsigned short* attb = ws + 4 * SD;                    // alias qhb

  CvtArgs ca;
  ca.src[0] = Wq; ca.dst[0] = wqb;
  ca.src[1] = Wk; ca.dst[1] = wkb;
  ca.src[2] = Wv; ca.dst[2] = wvb;
  ca.src[3] = Wo; ca.dst[3] = wob;
  cvt_kernel<<<dim3(288, 4), 256, 0, stream>>>(ca);   // DD/(8*256) = 288

  QkvArgs qa;
  qa.A[0] = q; qa.W[0] = wqb; qa.bias[0] = bq; qa.dst[0] = qhb;
  qa.scale[0] = 0.18033688011112042f;  // (1/8) * log2(e)
  qa.A[1] = k; qa.W[1] = wkb; qa.bias[1] = bk; qa.dst[1] = khb;
  qa.scale[1] = 1.0f;
  qa.A[2] = v; qa.W[2] = wvb; qa.bias[2] = bv; qa.dst[2] = vtb;
  qa.scale[2] = 1.0f;
  qkv_gemm<<<dim3(32, 6, 3), 256, 0, stream>>>(qa);

  attn_kernel<<<dim3(S_LEN / 256, NHEAD, 4), 256, 0, stream>>>(
      qhb, khb, vtb, pacc, prs);

  combine_kernel<<<dim3((NHEAD * S_LEN * 16) / 256), 256, 0, stream>>>(
      pacc, prs, attb);

  gemm_out<<<dim3(32, 6), 256, 0, stream>>>(attb, wob, bo, out);
}